// Round 9
// baseline (124.000 us; speedup 1.0000x reference)
//
#include <hip/hip_runtime.h>

typedef _Float16 half8 __attribute__((ext_vector_type(8)));
typedef _Float16 half4 __attribute__((ext_vector_type(4)));
typedef float    f32x4 __attribute__((ext_vector_type(4)));

#define T_TOK 16384
#define D_DIM 4096
#define E_EXP 128
#define CAP   256
#define BM    32
#define NT    16   // macro K-steps per pipe, BK=128 each (K per pipe = 2048)

// A LDS: [pipe][buf][row 0..31][512 B]. Per row: 4 ks-blocks of 128 B (k=32).
// Within each 128B block: 8 chunks of 16B; h at chunk (g ^ (row&7)), m at
// ((g|4) ^ (row&7)), g = k-group 0..3. ds_read_b128: each 8-lane HW phase
// covers 8 distinct bank-quads (conflict-free); ds_write_b64 phases are
// 2-way (free, m136). Row stride 512 =- 0 mod 128B keeps the analysis exact.
#define A_BUF_SZ  16384
#define A_PIPE_SZ 32768

// ---------------------------------------------------------------------------
// Kernel 0: wg (fp32) -> K-substep-tiled split-fp16 planes, scaled by 64.
// Substep s (k=32) block: h plane 8192 B | m plane 8192 B; expert e at e*64 B.
// ---------------------------------------------------------------------------
__global__ __launch_bounds__(256) void prep_wt(
    const float* __restrict__ wg, _Float16* __restrict__ wt)
{
    const int t = blockIdx.x * 256 + threadIdx.x;  // 65536 threads
    const int c = t & 3;
    const int e = (t >> 2) & 127;
    const int s = t >> 9;

    const float* src = wg + (size_t)e * D_DIM + s * 32 + c * 8;
    const f32x4 v0 = *reinterpret_cast<const f32x4*>(src);
    const f32x4 v1 = *reinterpret_cast<const f32x4*>(src + 4);

    half8 h, m;
#pragma unroll
    for (int j = 0; j < 4; j++) {
        float sv = v0[j] * 64.0f;
        _Float16 hh = (_Float16)sv;
        h[j] = hh; m[j] = (_Float16)(sv - (float)hh);
        sv = v1[j] * 64.0f;
        hh = (_Float16)sv;
        h[4 + j] = hh; m[4 + j] = (_Float16)(sv - (float)hh);
    }
    _Float16* dst = wt + (size_t)s * 8192 + e * 32 + c * 8;
    *reinterpret_cast<half8*>(dst)        = h;
    *reinterpret_cast<half8*>(dst + 4096) = m;
}

// ---------------------------------------------------------------------------
// Kernel A: dual-K-pipe MFMA GEMM + fused gate epilogue + idx1 histogram.
// 512 thr = 8 waves; waves 0-3 = K-half 0, waves 4-7 = K-half 1.
// BK=128 per barrier (4 substeps of 32): 96 MFMA/wave per barrier interval.
// A: x -> regs (1 macro-step ahead) -> fp16 h/m split -> swizzled LDS dbuf.
// B: registers, ping-pong P/Q sets prefetched ONE SUBSTEP ahead (32 VGPR,
//    fits the 128-cap so the compiler keeps the loads hoisted).
// Barrier = s_waitcnt lgkmcnt(0) + s_barrier (vmem stays in flight).
// ---------------------------------------------------------------------------
__global__ __launch_bounds__(512, 4) void gemm_gate(
    const float* __restrict__ x, const _Float16* __restrict__ wt,
    float* __restrict__ out, float* __restrict__ me, int* __restrict__ cnt1)
{
    __shared__ char smem[4 * A_BUF_SZ];    // 64 KB A tiles; logits alias after

    const int tid  = threadIdx.x;
    const int row0 = blockIdx.x * BM;
    const int lane = tid & 63;
    const int w    = tid >> 6;
    const int kp   = w >> 2;     // K-pipe 0/1
    const int wl   = w & 3;      // expert group: experts wl*32 .. +32
    const int lr   = lane & 15;
    const int lq   = lane >> 4;

    // ---- A staging role: threads 0-255 stage pipe 0, 256-511 pipe 1 ----
    const int sp   = tid >> 8;
    const int srow = (tid >> 3) & 31;
    const int sg   = tid & 7;
    const float* xA = x + (size_t)(row0 + srow) * D_DIM + sp * 2048 + sg * 4;
    const int awr_h = sp * A_PIPE_SZ + srow * 512 +
                      (((sg >> 1)    ) ^ (srow & 7)) * 16 + (sg & 1) * 8;
    const int awr_m = sp * A_PIPE_SZ + srow * 512 +
                      (((sg >> 1) | 4) ^ (srow & 7)) * 16 + (sg & 1) * 8;
    // + buf*A_BUF_SZ + ks*128

    // ---- A fragment read offsets (pipe kp) ----
    const int ah_ch = ((lq    ) ^ (lr & 7)) * 16;
    const int am_ch = ((lq | 4) ^ (lr & 7)) * 16;
    const char* const ard = smem + kp * A_PIPE_SZ;
    // + cur*A_BUF_SZ + (rf*16+lr)*512 + ks*128 + {ah_ch, am_ch}

    // ---- B fragment base: global substep s = kp*64 + 4t + ks ----
    const _Float16* const wtB =
        wt + (size_t)(kp * 64) * 8192 + (wl * 32 + lr) * 32 + lq * 8;

    f32x4 acc[2][2];
#pragma unroll
    for (int i = 0; i < 2; i++)
#pragma unroll
        for (int j = 0; j < 2; j++) acc[i][j] = (f32x4)0.0f;

// Load one substep's B fragments (4 x half8 = 16 VGPR) from L2-hot wt.
#define LOAD_BSS(Bh, Bm, s)                                                   \
    {                                                                         \
        const _Float16* bp = wtB + (size_t)((s) & 63) * 8192;                 \
        Bh[0] = *reinterpret_cast<const half8*>(bp);                          \
        Bh[1] = *reinterpret_cast<const half8*>(bp + 512);                    \
        Bm[0] = *reinterpret_cast<const half8*>(bp + 4096);                   \
        Bm[1] = *reinterpret_cast<const half8*>(bp + 4096 + 512);             \
    }

#define CONV_WRITE(av, buf)                                                   \
    {                                                                         \
        _Pragma("unroll") for (int ks = 0; ks < 4; ks++) {                    \
            half4 h, m;                                                       \
            _Pragma("unroll") for (int j = 0; j < 4; j++) {                   \
                const _Float16 hh = (_Float16)av[ks][j];                      \
                h[j] = hh; m[j] = (_Float16)(av[ks][j] - (float)hh);          \
            }                                                                 \
            char* const wb = smem + (buf) * A_BUF_SZ + ks * 128;              \
            *reinterpret_cast<half4*>(wb + awr_h) = h;                        \
            *reinterpret_cast<half4*>(wb + awr_m) = m;                        \
        }                                                                     \
    }

#define BAR()                                                                 \
    asm volatile("s_waitcnt lgkmcnt(0)" ::: "memory");                        \
    __builtin_amdgcn_sched_barrier(0);                                        \
    __builtin_amdgcn_s_barrier();                                             \
    __builtin_amdgcn_sched_barrier(0);

#define SUBSTEP(cur, ks, Bh, Bm)                                              \
    {                                                                         \
        half8 Ah[2], Am[2];                                                   \
        _Pragma("unroll") for (int rf = 0; rf < 2; rf++) {                    \
            const char* ab = ard + (cur) * A_BUF_SZ +                         \
                             (rf * 16 + lr) * 512 + (ks) * 128;               \
            Ah[rf] = *reinterpret_cast<const half8*>(ab + ah_ch);             \
            Am[rf] = *reinterpret_cast<const half8*>(ab + am_ch);             \
        }                                                                     \
        __builtin_amdgcn_s_setprio(1);                                        \
        _Pragma("unroll") for (int rf = 0; rf < 2; rf++)                      \
            _Pragma("unroll") for (int cf = 0; cf < 2; cf++) {                \
                acc[rf][cf] = __builtin_amdgcn_mfma_f32_16x16x32_f16(         \
                    Am[rf], Bh[cf], acc[rf][cf], 0, 0, 0);                    \
                acc[rf][cf] = __builtin_amdgcn_mfma_f32_16x16x32_f16(         \
                    Ah[rf], Bm[cf], acc[rf][cf], 0, 0, 0);                    \
                acc[rf][cf] = __builtin_amdgcn_mfma_f32_16x16x32_f16(         \
                    Ah[rf], Bh[cf], acc[rf][cf], 0, 0, 0);                    \
            }                                                                 \
        __builtin_amdgcn_s_setprio(0);                                        \
    }

// Macro-step t: A(t+1)->regs at top; B ping-pong P/Q one substep ahead;
// stage A(t+1) to LDS at bottom; one barrier.  Invariant on entry: P holds
// B(4t); on exit: P holds B(4t+4).
#define STEP(cur, t)                                                          \
    {                                                                         \
        const int kn = (((t) + 1) & (NT - 1)) * 128;                          \
        f32x4 avN[4];                                                         \
        avN[0] = *reinterpret_cast<const f32x4*>(xA + kn);                    \
        avN[1] = *reinterpret_cast<const f32x4*>(xA + kn + 32);               \
        avN[2] = *reinterpret_cast<const f32x4*>(xA + kn + 64);               \
        avN[3] = *reinterpret_cast<const f32x4*>(xA + kn + 96);               \
        const int s0 = 4 * (t);                                               \
        LOAD_BSS(QBh, QBm, s0 + 1);  SUBSTEP(cur, 0, PBh, PBm);               \
        LOAD_BSS(PBh, PBm, s0 + 2);  SUBSTEP(cur, 1, QBh, QBm);               \
        LOAD_BSS(QBh, QBm, s0 + 3);  SUBSTEP(cur, 2, PBh, PBm);               \
        LOAD_BSS(PBh, PBm, s0 + 4);  SUBSTEP(cur, 3, QBh, QBm);               \
        CONV_WRITE(avN, (cur) ^ 1);                                           \
        BAR();                                                                \
    }

    half8 PBh[2], PBm[2], QBh[2], QBm[2];

    // ---- prologue: A(0) -> buf0; B(0) -> P ----
    {
        f32x4 av0[4];
        av0[0] = *reinterpret_cast<const f32x4*>(xA);
        av0[1] = *reinterpret_cast<const f32x4*>(xA + 32);
        av0[2] = *reinterpret_cast<const f32x4*>(xA + 64);
        av0[3] = *reinterpret_cast<const f32x4*>(xA + 96);
        LOAD_BSS(PBh, PBm, 0);
        CONV_WRITE(av0, 0);
        BAR();
    }

    // ---- main loop: 16 macro-steps, 2 per iteration (static indices) ----
    for (int t = 0; t < NT; t += 2) {
        STEP(0, t);
        STEP(1, t + 1);
    }

#undef STEP
#undef SUBSTEP
#undef BAR
#undef CONV_WRITE
#undef LOAD_BSS

    // ---- merge the two K-pipes into lg (aliases A smem), scale by 1/64 ----
    float* lg = reinterpret_cast<float*>(smem);   // [32][129]
    if (kp == 1) {
#pragma unroll
        for (int rf = 0; rf < 2; rf++)
#pragma unroll
            for (int cf = 0; cf < 2; cf++)
#pragma unroll
                for (int r = 0; r < 4; r++)
                    lg[(rf * 16 + lq * 4 + r) * 129 + wl * 32 + cf * 16 + lr] =
                        acc[rf][cf][r] * 0.015625f;
    }
    __syncthreads();
    if (kp == 0) {
#pragma unroll
        for (int rf = 0; rf < 2; rf++)
#pragma unroll
            for (int cf = 0; cf < 2; cf++)
#pragma unroll
                for (int r = 0; r < 4; r++)
                    lg[(rf * 16 + lq * 4 + r) * 129 + wl * 32 + cf * 16 + lr] +=
                        acc[rf][cf][r] * 0.015625f;
    }
    __syncthreads();

    // ---- gate epilogue ----
    if (tid < BM) {
        const int r = tid;
        const int t = row0 + r;
        float m1 = -1e30f, m2 = -1e30f;
        int   i1 = 0, i2 = 0;
        for (int e = 0; e < E_EXP; e++) {
            const float v = lg[r * 129 + e];
            if (v > m1)      { m2 = m1; i2 = i1; m1 = v; i1 = e; }
            else if (v > m2) { m2 = v; i2 = e; }
        }
        float s = 0.0f;
        for (int e = 0; e < E_EXP; e++) s += __expf(lg[r * 129 + e] - m1);
        const float inv = 1.0f / s;

        out[3 + 0 * T_TOK + t] = (float)i1;
        out[3 + 1 * T_TOK + t] = (float)i2;
        out[3 + 4 * T_TOK + t] = inv;
        out[3 + 5 * T_TOK + t] = __expf(m2 - m1) * inv;
        atomicAdd(&cnt1[i1], 1);

        for (int e = 0; e < E_EXP; e++)
            lg[r * 129 + e] = __expf(lg[r * 129 + e] - m1) * inv;
    }
    __syncthreads();

    if (tid < E_EXP) {
        float s = 0.0f;
        for (int r = 0; r < BM; r++) s += lg[r * 129 + tid];
        atomicAdd(&me[tid], s);
    }
}

// ---------------------------------------------------------------------------
// Kernel B: per-expert rank. 256 blocks x 1024 thr: blocks 0-127 scan idx1;
// blocks 128-255 scan idx2 starting at base = cnt1[e] (from gemm histogram).
// ---------------------------------------------------------------------------
__global__ __launch_bounds__(1024) void rank_kernel(
    float* __restrict__ out, const int* __restrict__ cnt1)
{
    const int  e      = blockIdx.x & 127;
    const bool second = blockIdx.x >= 128;
    const int  tid    = threadIdx.x;
    const int  lane   = tid & 63;
    const int  w      = tid >> 6;   // 0..15

    __shared__ int wtot[16];

    const float* idxA = out + 3 + (second ? T_TOK : 0);
    float* loc = out + 3 + (second ? 3 * T_TOK : 2 * T_TOK);

    const unsigned long long below = (1ull << lane) - 1ull;
    int base = second ? cnt1[e] : 0;

    for (int t0 = 0; t0 < T_TOK; t0 += 1024) {
        const int t = t0 + tid;
        const int f = ((int)idxA[t] == e);
        const unsigned long long m = __ballot(f);
        const int pre = __popcll(m & below);
        const int tot = __popcll(m);
        if (lane == 0) wtot[w] = tot;
        __syncthreads();
        int off = 0, all = 0;
#pragma unroll
        for (int i = 0; i < 16; i++) {
            const int v = wtot[i];
            if (i < w) off += v;
            all += v;
        }
        if (f) {
            const int rank = base + off + pre;
            loc[t] = (rank < CAP) ? (float)rank : 0.0f;
        }
        base += all;
        __syncthreads();
    }
}

// ---------------------------------------------------------------------------
// Kernel C: l_aux = sum(me * min(cnt1,CAP)) * E/(T*T); plus constants.
// ---------------------------------------------------------------------------
__global__ __launch_bounds__(128) void finalize_kernel(
    const float* __restrict__ me, const int* __restrict__ cnt1,
    float* __restrict__ out)
{
    __shared__ float red[2];
    const int tid = threadIdx.x;
    const int c = cnt1[tid];
    float p = me[tid] * (float)((c < CAP) ? c : CAP);
#pragma unroll
    for (int o = 32; o > 0; o >>= 1) p += __shfl_down(p, o);
    if ((tid & 63) == 0) red[tid >> 6] = p;
    __syncthreads();
    if (tid == 0) {
        const float tot = red[0] + red[1];
        out[0] = tot * ((float)E_EXP / ((float)T_TOK * (float)T_TOK));
        out[1] = (float)CAP;
        out[2] = (float)E_EXP;
    }
}

extern "C" void kernel_launch(void* const* d_in, const int* in_sizes, int n_in,
                              void* d_out, int out_size, void* d_ws, size_t ws_size,
                              hipStream_t stream)
{
    const float* x  = (const float*)d_in[0];
    const float* wg = (const float*)d_in[1];
    float* out = (float*)d_out;

    float* me   = (float*)d_ws;                      // 128 floats
    int*   cnt1 = (int*)((char*)d_ws + 512);         // 128 ints
    _Float16* wt = (_Float16*)((char*)d_ws + 1024);  // 2 MB K-tiled planes

    hipMemsetAsync(d_ws, 0, 1024, stream);
    prep_wt<<<256, 256, 0, stream>>>(wg, wt);
    gemm_gate<<<T_TOK / BM, 512, 0, stream>>>(x, wt, out, me, cnt1);
    rank_kernel<<<2 * E_EXP, 1024, 0, stream>>>(out, cnt1);
    finalize_kernel<<<1, 128, 0, stream>>>(me, cnt1, out);
}

// Round 10
// 118.321 us; speedup vs baseline: 1.0480x; 1.0480x over previous
//
#include <hip/hip_runtime.h>

typedef _Float16 half8 __attribute__((ext_vector_type(8)));
typedef _Float16 half4 __attribute__((ext_vector_type(4)));
typedef float    f32x4 __attribute__((ext_vector_type(4)));

#define T_TOK 16384
#define D_DIM 4096
#define E_EXP 128
#define CAP   256
#define BM    64
#define NT    32   // macro K-steps per pipe, BK=64 each (K per pipe = 2048)

// A LDS: [pipe][buf][row 0..63][256 B]. Per row: 2 ks-blocks of 128 B (k=32).
// Within each 128B block: 8 chunks of 16B; h at chunk (g ^ (row&7)), m at
// ((g|4) ^ (row&7)), g = k-group 0..3. Row stride 256 B == 0 mod 32 banks, so
// bank = chunk*4: write phases are 2-way aliased (free, m136), read phases
// (lq ^ (lr&7)) cover 8 distinct bank-quads -> conflict-free.
#define A_BUF_SZ  16384
#define A_PIPE_SZ 32768

// ---------------------------------------------------------------------------
// Kernel 0: wg (fp32) -> K-substep-tiled split-fp16 planes, scaled by 64.
// Substep s (k=32) block: h plane 8192 B | m plane 8192 B; expert e at e*64 B.
// ---------------------------------------------------------------------------
__global__ __launch_bounds__(256) void prep_wt(
    const float* __restrict__ wg, _Float16* __restrict__ wt)
{
    const int t = blockIdx.x * 256 + threadIdx.x;  // 65536 threads
    const int c = t & 3;
    const int e = (t >> 2) & 127;
    const int s = t >> 9;

    const float* src = wg + (size_t)e * D_DIM + s * 32 + c * 8;
    const f32x4 v0 = *reinterpret_cast<const f32x4*>(src);
    const f32x4 v1 = *reinterpret_cast<const f32x4*>(src + 4);

    half8 h, m;
#pragma unroll
    for (int j = 0; j < 4; j++) {
        float sv = v0[j] * 64.0f;
        _Float16 hh = (_Float16)sv;
        h[j] = hh; m[j] = (_Float16)(sv - (float)hh);
        sv = v1[j] * 64.0f;
        hh = (_Float16)sv;
        h[4 + j] = hh; m[4 + j] = (_Float16)(sv - (float)hh);
    }
    _Float16* dst = wt + (size_t)s * 8192 + e * 32 + c * 8;
    *reinterpret_cast<half8*>(dst)        = h;
    *reinterpret_cast<half8*>(dst + 4096) = m;
}

// ---------------------------------------------------------------------------
// Kernel A: BM=64 dual-K-pipe MFMA GEMM + fused gate epilogue + idx1 histo.
// 1024 thr = 16 waves = 2 K-pipes x 8 expert-groups (16 experts each).
// Wave tile: 64 rows x 16 experts (4 rf x 1 cf), K=2048 per pipe.
// Per-CU TCP bytes: B 2 MB + A 1 MB (vs 5 MB at BM=32) -> floor ~20 us.
// A: x -> regs (in-step) -> fp16 h/m split -> XOR-swizzled LDS dbuf.
// B: K-tiled wt planes direct to registers (contiguous 1KB wave-bursts, L2).
// Barrier = s_waitcnt lgkmcnt(0) + s_barrier (vmem stays in flight).
// ---------------------------------------------------------------------------
__global__ __launch_bounds__(1024, 4) void gemm_gate(
    const float* __restrict__ x, const _Float16* __restrict__ wt,
    float* __restrict__ out, float* __restrict__ me, int* __restrict__ cnt1)
{
    __shared__ char smem[2 * A_PIPE_SZ];   // 64 KB A tiles; logits alias after

    const int tid  = threadIdx.x;
    const int row0 = blockIdx.x * BM;
    const int lane = tid & 63;
    const int w    = tid >> 6;
    const int kp   = w >> 3;     // K-pipe 0/1
    const int wl   = w & 7;      // expert group: experts wl*16 .. +16
    const int lr   = lane & 15;
    const int lq   = lane >> 4;

    // ---- A staging role: threads 0-511 stage pipe 0, 512-1023 pipe 1 ----
    // Each thread: 8 floats of row srow, k-span sg*8 within the 64-chunk.
    const int sp   = tid >> 9;
    const int srow = (tid >> 3) & 63;
    const int sg   = tid & 7;
    const float* xA = x + (size_t)(row0 + srow) * D_DIM + sp * 2048 + sg * 8;
    const int awr_h = sp * A_PIPE_SZ + srow * 256 + (sg >> 2) * 128 +
                      (((sg & 3)    ) ^ (srow & 7)) * 16;
    const int awr_m = sp * A_PIPE_SZ + srow * 256 + (sg >> 2) * 128 +
                      (((sg & 3) | 4) ^ (srow & 7)) * 16;
    // + buf*A_BUF_SZ

    // ---- A fragment read offsets (pipe kp) ----
    const int ah_ch = ((lq    ) ^ (lr & 7)) * 16;
    const int am_ch = ((lq | 4) ^ (lr & 7)) * 16;
    const char* const ard = smem + kp * A_PIPE_SZ;
    // + cur*A_BUF_SZ + (rf*16+lr)*256 + ks*128 + {ah_ch, am_ch}

    // ---- B fragment base: global substep s = kp*64 + 2t + ks ----
    const _Float16* const wtB =
        wt + (size_t)(kp * 64) * 8192 + (wl * 16 + lr) * 32 + lq * 8;

    f32x4 acc[4];
#pragma unroll
    for (int i = 0; i < 4; i++) acc[i] = (f32x4)0.0f;

#define CONV_WRITE(a0, a1, buf)                                               \
    {                                                                         \
        half8 h, m;                                                           \
        _Pragma("unroll") for (int j = 0; j < 4; j++) {                       \
            _Float16 hh = (_Float16)a0[j];                                    \
            h[j] = hh; m[j] = (_Float16)(a0[j] - (float)hh);                  \
            hh = (_Float16)a1[j];                                             \
            h[4 + j] = hh; m[4 + j] = (_Float16)(a1[j] - (float)hh);          \
        }                                                                     \
        char* const wb = smem + (buf) * A_BUF_SZ;                             \
        *reinterpret_cast<half8*>(wb + awr_h) = h;                            \
        *reinterpret_cast<half8*>(wb + awr_m) = m;                            \
    }

#define BAR()                                                                 \
    asm volatile("s_waitcnt lgkmcnt(0)" ::: "memory");                        \
    __builtin_amdgcn_sched_barrier(0);                                        \
    __builtin_amdgcn_s_barrier();                                             \
    __builtin_amdgcn_sched_barrier(0);

#define SUBSTEP(cur, ks, t)                                                   \
    {                                                                         \
        const _Float16* bp = wtB + (size_t)((2 * (t) + (ks)) & 63) * 8192;    \
        const half8 Bh = *reinterpret_cast<const half8*>(bp);                 \
        const half8 Bm = *reinterpret_cast<const half8*>(bp + 4096);          \
        half8 Ah[4], Am[4];                                                   \
        _Pragma("unroll") for (int rf = 0; rf < 4; rf++) {                    \
            const char* ab = ard + (cur) * A_BUF_SZ +                         \
                             (rf * 16 + lr) * 256 + (ks) * 128;               \
            Ah[rf] = *reinterpret_cast<const half8*>(ab + ah_ch);             \
            Am[rf] = *reinterpret_cast<const half8*>(ab + am_ch);             \
        }                                                                     \
        _Pragma("unroll") for (int rf = 0; rf < 4; rf++) {                    \
            acc[rf] = __builtin_amdgcn_mfma_f32_16x16x32_f16(                 \
                Am[rf], Bh, acc[rf], 0, 0, 0);                                \
            acc[rf] = __builtin_amdgcn_mfma_f32_16x16x32_f16(                 \
                Ah[rf], Bm, acc[rf], 0, 0, 0);                                \
            acc[rf] = __builtin_amdgcn_mfma_f32_16x16x32_f16(                 \
                Ah[rf], Bh, acc[rf], 0, 0, 0);                                \
        }                                                                     \
    }

// Macro-step t: A(t+1)->regs at top; compute substeps of t (B loaded in-step,
// proven best in R7); stage A(t+1) to LDS at bottom; one lgkm-only barrier.
#define STEP(cur, t)                                                          \
    {                                                                         \
        const int kn = (((t) + 1) & (NT - 1)) * 64;                           \
        const f32x4 a0 = *reinterpret_cast<const f32x4*>(xA + kn);            \
        const f32x4 a1 = *reinterpret_cast<const f32x4*>(xA + kn + 4);        \
        SUBSTEP(cur, 0, t);                                                   \
        SUBSTEP(cur, 1, t);                                                   \
        CONV_WRITE(a0, a1, (cur) ^ 1);                                        \
        BAR();                                                                \
    }

    // ---- prologue: A(0) -> buf0 ----
    {
        const f32x4 a0 = *reinterpret_cast<const f32x4*>(xA);
        const f32x4 a1 = *reinterpret_cast<const f32x4*>(xA + 4);
        CONV_WRITE(a0, a1, 0);
        BAR();
    }

    // ---- main loop: 32 macro-steps, 2 per iteration (static indices) ----
    for (int t = 0; t < NT; t += 2) {
        STEP(0, t);
        STEP(1, t + 1);
    }

#undef STEP
#undef SUBSTEP
#undef BAR
#undef CONV_WRITE

    // ---- merge the two K-pipes into lg (aliases A smem), scale by 1/64 ----
    float* lg = reinterpret_cast<float*>(smem);   // [64][129] = 33 KB
    if (kp == 1) {
#pragma unroll
        for (int rf = 0; rf < 4; rf++)
#pragma unroll
            for (int r = 0; r < 4; r++)
                lg[(rf * 16 + lq * 4 + r) * 129 + wl * 16 + lr] =
                    acc[rf][r] * 0.015625f;
    }
    __syncthreads();
    if (kp == 0) {
#pragma unroll
        for (int rf = 0; rf < 4; rf++)
#pragma unroll
            for (int r = 0; r < 4; r++)
                lg[(rf * 16 + lq * 4 + r) * 129 + wl * 16 + lr] +=
                    acc[rf][r] * 0.015625f;
    }
    __syncthreads();

    // ---- gate epilogue ----
    if (tid < BM) {
        const int r = tid;
        const int t = row0 + r;
        float m1 = -1e30f, m2 = -1e30f;
        int   i1 = 0, i2 = 0;
        for (int e = 0; e < E_EXP; e++) {
            const float v = lg[r * 129 + e];
            if (v > m1)      { m2 = m1; i2 = i1; m1 = v; i1 = e; }
            else if (v > m2) { m2 = v; i2 = e; }
        }
        float s = 0.0f;
        for (int e = 0; e < E_EXP; e++) s += __expf(lg[r * 129 + e] - m1);
        const float inv = 1.0f / s;

        out[3 + 0 * T_TOK + t] = (float)i1;
        out[3 + 1 * T_TOK + t] = (float)i2;
        out[3 + 4 * T_TOK + t] = inv;
        out[3 + 5 * T_TOK + t] = __expf(m2 - m1) * inv;
        atomicAdd(&cnt1[i1], 1);

        for (int e = 0; e < E_EXP; e++)
            lg[r * 129 + e] = __expf(lg[r * 129 + e] - m1) * inv;
    }
    __syncthreads();

    if (tid < E_EXP) {
        float s = 0.0f;
        for (int r = 0; r < BM; r++) s += lg[r * 129 + tid];
        atomicAdd(&me[tid], s);
    }
}

// ---------------------------------------------------------------------------
// Kernel B: per-expert rank. 256 blocks x 1024 thr: blocks 0-127 scan idx1;
// blocks 128-255 scan idx2 starting at base = cnt1[e] (from gemm histogram).
// ---------------------------------------------------------------------------
__global__ __launch_bounds__(1024) void rank_kernel(
    float* __restrict__ out, const int* __restrict__ cnt1)
{
    const int  e      = blockIdx.x & 127;
    const bool second = blockIdx.x >= 128;
    const int  tid    = threadIdx.x;
    const int  lane   = tid & 63;
    const int  w      = tid >> 6;   // 0..15

    __shared__ int wtot[16];

    const float* idxA = out + 3 + (second ? T_TOK : 0);
    float* loc = out + 3 + (second ? 3 * T_TOK : 2 * T_TOK);

    const unsigned long long below = (1ull << lane) - 1ull;
    int base = second ? cnt1[e] : 0;

    for (int t0 = 0; t0 < T_TOK; t0 += 1024) {
        const int t = t0 + tid;
        const int f = ((int)idxA[t] == e);
        const unsigned long long m = __ballot(f);
        const int pre = __popcll(m & below);
        const int tot = __popcll(m);
        if (lane == 0) wtot[w] = tot;
        __syncthreads();
        int off = 0, all = 0;
#pragma unroll
        for (int i = 0; i < 16; i++) {
            const int v = wtot[i];
            if (i < w) off += v;
            all += v;
        }
        if (f) {
            const int rank = base + off + pre;
            loc[t] = (rank < CAP) ? (float)rank : 0.0f;
        }
        base += all;
        __syncthreads();
    }
}

// ---------------------------------------------------------------------------
// Kernel C: l_aux = sum(me * min(cnt1,CAP)) * E/(T*T); plus constants.
// ---------------------------------------------------------------------------
__global__ __launch_bounds__(128) void finalize_kernel(
    const float* __restrict__ me, const int* __restrict__ cnt1,
    float* __restrict__ out)
{
    __shared__ float red[2];
    const int tid = threadIdx.x;
    const int c = cnt1[tid];
    float p = me[tid] * (float)((c < CAP) ? c : CAP);
#pragma unroll
    for (int o = 32; o > 0; o >>= 1) p += __shfl_down(p, o);
    if ((tid & 63) == 0) red[tid >> 6] = p;
    __syncthreads();
    if (tid == 0) {
        const float tot = red[0] + red[1];
        out[0] = tot * ((float)E_EXP / ((float)T_TOK * (float)T_TOK));
        out[1] = (float)CAP;
        out[2] = (float)E_EXP;
    }
}

extern "C" void kernel_launch(void* const* d_in, const int* in_sizes, int n_in,
                              void* d_out, int out_size, void* d_ws, size_t ws_size,
                              hipStream_t stream)
{
    const float* x  = (const float*)d_in[0];
    const float* wg = (const float*)d_in[1];
    float* out = (float*)d_out;

    float* me   = (float*)d_ws;                      // 128 floats
    int*   cnt1 = (int*)((char*)d_ws + 512);         // 128 ints
    _Float16* wt = (_Float16*)((char*)d_ws + 1024);  // 2 MB K-tiled planes

    hipMemsetAsync(d_ws, 0, 1024, stream);
    prep_wt<<<256, 256, 0, stream>>>(wg, wt);
    gemm_gate<<<T_TOK / BM, 1024, 0, stream>>>(x, wt, out, me, cnt1);
    rank_kernel<<<2 * E_EXP, 1024, 0, stream>>>(out, cnt1);
    finalize_kernel<<<1, 128, 0, stream>>>(me, cnt1, out);
}

// Round 11
// 114.196 us; speedup vs baseline: 1.0858x; 1.0361x over previous
//
#include <hip/hip_runtime.h>

typedef _Float16 half8 __attribute__((ext_vector_type(8)));
typedef _Float16 half4 __attribute__((ext_vector_type(4)));
typedef float    f32x4 __attribute__((ext_vector_type(4)));

#define T_TOK 16384
#define D_DIM 4096
#define E_EXP 128
#define CAP   256
#define BM    64
#define NT    32   // macro K-steps per pipe, BK=64 each (K per pipe = 2048)

// A LDS: [pipe][buf][row 0..63][256 B]. Per row: 2 ks-blocks of 128 B (k=32).
// Within each 128B block: 8 chunks of 16B; h at chunk (g ^ (row&7)), m at
// ((g|4) ^ (row&7)), g = k-group 0..3. Write phases 2-way aliased (free),
// read phases conflict-free (verified R10 layout).
#define A_BUF_SZ  16384
#define A_PIPE_SZ 32768

// ---------------------------------------------------------------------------
// Kernel 0: wg (fp32) -> K-substep-tiled split-fp16 planes, scaled by 64.
// Substep s (k=32) block: h plane 8192 B | m plane 8192 B; expert e at e*64 B.
// ---------------------------------------------------------------------------
__global__ __launch_bounds__(256) void prep_wt(
    const float* __restrict__ wg, _Float16* __restrict__ wt)
{
    const int t = blockIdx.x * 256 + threadIdx.x;  // 65536 threads
    const int c = t & 3;
    const int e = (t >> 2) & 127;
    const int s = t >> 9;

    const float* src = wg + (size_t)e * D_DIM + s * 32 + c * 8;
    const f32x4 v0 = *reinterpret_cast<const f32x4*>(src);
    const f32x4 v1 = *reinterpret_cast<const f32x4*>(src + 4);

    half8 h, m;
#pragma unroll
    for (int j = 0; j < 4; j++) {
        float sv = v0[j] * 64.0f;
        _Float16 hh = (_Float16)sv;
        h[j] = hh; m[j] = (_Float16)(sv - (float)hh);
        sv = v1[j] * 64.0f;
        hh = (_Float16)sv;
        h[4 + j] = hh; m[4 + j] = (_Float16)(sv - (float)hh);
    }
    _Float16* dst = wt + (size_t)s * 8192 + e * 32 + c * 8;
    *reinterpret_cast<half8*>(dst)        = h;
    *reinterpret_cast<half8*>(dst + 4096) = m;
}

// ---------------------------------------------------------------------------
// Kernel A: BM=64 dual-K-pipe MFMA GEMM + fused gate epilogue + idx1 histo.
// 1024 thr = 16 waves = 2 K-pipes x 8 expert-groups (16 experts each).
// CRITICAL ISSUE ORDER per step (the R11 fix): B(t) L2-loads FIRST, then
// A(t+2) HBM-loads, then MFMAs (vmcnt waits touch only B), then CONV_WRITE
// of A(t+1) (landed a full step ago, zero wait), then lgkm-only barrier.
// No in-step wait ever drains an in-flight HBM load.
// ---------------------------------------------------------------------------
__global__ __launch_bounds__(1024, 4) void gemm_gate(
    const float* __restrict__ x, const _Float16* __restrict__ wt,
    float* __restrict__ out, float* __restrict__ me, int* __restrict__ cnt1)
{
    __shared__ char smem[2 * A_PIPE_SZ];   // 64 KB A tiles; logits alias after

    const int tid  = threadIdx.x;
    const int row0 = blockIdx.x * BM;
    const int lane = tid & 63;
    const int w    = tid >> 6;
    const int kp   = w >> 3;     // K-pipe 0/1
    const int wl   = w & 7;      // expert group: experts wl*16 .. +16
    const int lr   = lane & 15;
    const int lq   = lane >> 4;

    // ---- A staging role: threads 0-511 stage pipe 0, 512-1023 pipe 1 ----
    const int sp   = tid >> 9;
    const int srow = (tid >> 3) & 63;
    const int sg   = tid & 7;
    const float* xA = x + (size_t)(row0 + srow) * D_DIM + sp * 2048 + sg * 8;
    const int awr_h = sp * A_PIPE_SZ + srow * 256 + (sg >> 2) * 128 +
                      (((sg & 3)    ) ^ (srow & 7)) * 16;
    const int awr_m = sp * A_PIPE_SZ + srow * 256 + (sg >> 2) * 128 +
                      (((sg & 3) | 4) ^ (srow & 7)) * 16;

    // ---- A fragment read offsets (pipe kp) ----
    const int ah_ch = ((lq    ) ^ (lr & 7)) * 16;
    const int am_ch = ((lq | 4) ^ (lr & 7)) * 16;
    const char* const ard = smem + kp * A_PIPE_SZ;

    // ---- B fragment base: global substep s = kp*64 + 2t + ks ----
    const _Float16* const wtB =
        wt + (size_t)(kp * 64) * 8192 + (wl * 16 + lr) * 32 + lq * 8;

    f32x4 acc[4];
#pragma unroll
    for (int i = 0; i < 4; i++) acc[i] = (f32x4)0.0f;

#define CONV_WRITE(a0, a1, buf)                                               \
    {                                                                         \
        half8 h, m;                                                           \
        _Pragma("unroll") for (int j = 0; j < 4; j++) {                       \
            _Float16 hh = (_Float16)a0[j];                                    \
            h[j] = hh; m[j] = (_Float16)(a0[j] - (float)hh);                  \
            hh = (_Float16)a1[j];                                             \
            h[4 + j] = hh; m[4 + j] = (_Float16)(a1[j] - (float)hh);          \
        }                                                                     \
        char* const wb = smem + (buf) * A_BUF_SZ;                             \
        *reinterpret_cast<half8*>(wb + awr_h) = h;                            \
        *reinterpret_cast<half8*>(wb + awr_m) = m;                            \
    }

#define BAR()                                                                 \
    asm volatile("s_waitcnt lgkmcnt(0)" ::: "memory");                        \
    __builtin_amdgcn_sched_barrier(0);                                        \
    __builtin_amdgcn_s_barrier();                                             \
    __builtin_amdgcn_sched_barrier(0);

#define SUBSTEP(cur, ks, Bh, Bm)                                              \
    {                                                                         \
        half8 Ah[4], Am[4];                                                   \
        _Pragma("unroll") for (int rf = 0; rf < 4; rf++) {                    \
            const char* ab = ard + (cur) * A_BUF_SZ +                         \
                             (rf * 16 + lr) * 256 + (ks) * 128;               \
            Ah[rf] = *reinterpret_cast<const half8*>(ab + ah_ch);             \
            Am[rf] = *reinterpret_cast<const half8*>(ab + am_ch);             \
        }                                                                     \
        _Pragma("unroll") for (int rf = 0; rf < 4; rf++) {                    \
            acc[rf] = __builtin_amdgcn_mfma_f32_16x16x32_f16(                 \
                Am[rf], Bh, acc[rf], 0, 0, 0);                                \
            acc[rf] = __builtin_amdgcn_mfma_f32_16x16x32_f16(                 \
                Ah[rf], Bm, acc[rf], 0, 0, 0);                                \
            acc[rf] = __builtin_amdgcn_mfma_f32_16x16x32_f16(                 \
                Ah[rf], Bh, acc[rf], 0, 0, 0);                                \
        }                                                                     \
    }

// Macro-step t. AC holds A(t+1) (loaded last step); AN receives A(t+2).
// Issue order is load-ordering-critical: B first (oldest), A after, so
// MFMA vmcnt waits never include an in-flight HBM load.
#define STEP(cur, t, AC0, AC1, AN0, AN1)                                      \
    {                                                                         \
        const _Float16* bp0 = wtB + (size_t)((2 * (t)    ) & 63) * 8192;      \
        const _Float16* bp1 = wtB + (size_t)((2 * (t) + 1) & 63) * 8192;      \
        const half8 Bh0 = *reinterpret_cast<const half8*>(bp0);               \
        const half8 Bm0 = *reinterpret_cast<const half8*>(bp0 + 4096);        \
        const half8 Bh1 = *reinterpret_cast<const half8*>(bp1);               \
        const half8 Bm1 = *reinterpret_cast<const half8*>(bp1 + 4096);        \
        __builtin_amdgcn_sched_barrier(0);                                    \
        const int kn = (((t) + 2) & (NT - 1)) * 64;                           \
        AN0 = *reinterpret_cast<const f32x4*>(xA + kn);                       \
        AN1 = *reinterpret_cast<const f32x4*>(xA + kn + 4);                   \
        __builtin_amdgcn_sched_barrier(0);                                    \
        SUBSTEP(cur, 0, Bh0, Bm0);                                            \
        SUBSTEP(cur, 1, Bh1, Bm1);                                            \
        CONV_WRITE(AC0, AC1, (cur) ^ 1);                                      \
        BAR();                                                                \
    }

    f32x4 aA0, aA1, aB0, aB1;

    // ---- prologue: A(0) -> buf0; A(1) -> regs ----
    {
        const f32x4 a00 = *reinterpret_cast<const f32x4*>(xA);
        const f32x4 a01 = *reinterpret_cast<const f32x4*>(xA + 4);
        aA0 = *reinterpret_cast<const f32x4*>(xA + 64);
        aA1 = *reinterpret_cast<const f32x4*>(xA + 68);
        CONV_WRITE(a00, a01, 0);
        BAR();
    }

    // ---- main loop: 32 macro-steps, 2 per iteration (static indices) ----
    for (int t = 0; t < NT; t += 2) {
        STEP(0, t,     aA0, aA1, aB0, aB1);
        STEP(1, t + 1, aB0, aB1, aA0, aA1);
    }

#undef STEP
#undef SUBSTEP
#undef BAR
#undef CONV_WRITE

    // ---- merge the two K-pipes into lg (aliases A smem), scale by 1/64 ----
    float* lg = reinterpret_cast<float*>(smem);   // [64][129] = 33 KB
    if (kp == 1) {
#pragma unroll
        for (int rf = 0; rf < 4; rf++)
#pragma unroll
            for (int r = 0; r < 4; r++)
                lg[(rf * 16 + lq * 4 + r) * 129 + wl * 16 + lr] =
                    acc[rf][r] * 0.015625f;
    }
    __syncthreads();
    if (kp == 0) {
#pragma unroll
        for (int rf = 0; rf < 4; rf++)
#pragma unroll
            for (int r = 0; r < 4; r++)
                lg[(rf * 16 + lq * 4 + r) * 129 + wl * 16 + lr] +=
                    acc[rf][r] * 0.015625f;
    }
    __syncthreads();

    // ---- gate epilogue ----
    if (tid < BM) {
        const int r = tid;
        const int t = row0 + r;
        float m1 = -1e30f, m2 = -1e30f;
        int   i1 = 0, i2 = 0;
        for (int e = 0; e < E_EXP; e++) {
            const float v = lg[r * 129 + e];
            if (v > m1)      { m2 = m1; i2 = i1; m1 = v; i1 = e; }
            else if (v > m2) { m2 = v; i2 = e; }
        }
        float s = 0.0f;
        for (int e = 0; e < E_EXP; e++) s += __expf(lg[r * 129 + e] - m1);
        const float inv = 1.0f / s;

        out[3 + 0 * T_TOK + t] = (float)i1;
        out[3 + 1 * T_TOK + t] = (float)i2;
        out[3 + 4 * T_TOK + t] = inv;
        out[3 + 5 * T_TOK + t] = __expf(m2 - m1) * inv;
        atomicAdd(&cnt1[i1], 1);

        for (int e = 0; e < E_EXP; e++)
            lg[r * 129 + e] = __expf(lg[r * 129 + e] - m1) * inv;
    }
    __syncthreads();

    if (tid < E_EXP) {
        float s = 0.0f;
        for (int r = 0; r < BM; r++) s += lg[r * 129 + tid];
        atomicAdd(&me[tid], s);
    }
}

// ---------------------------------------------------------------------------
// Kernel B: per-expert rank. 256 blocks x 1024 thr: blocks 0-127 scan idx1;
// blocks 128-255 scan idx2 starting at base = cnt1[e] (from gemm histogram).
// ---------------------------------------------------------------------------
__global__ __launch_bounds__(1024) void rank_kernel(
    float* __restrict__ out, const int* __restrict__ cnt1)
{
    const int  e      = blockIdx.x & 127;
    const bool second = blockIdx.x >= 128;
    const int  tid    = threadIdx.x;
    const int  lane   = tid & 63;
    const int  w      = tid >> 6;   // 0..15

    __shared__ int wtot[16];

    const float* idxA = out + 3 + (second ? T_TOK : 0);
    float* loc = out + 3 + (second ? 3 * T_TOK : 2 * T_TOK);

    const unsigned long long below = (1ull << lane) - 1ull;
    int base = second ? cnt1[e] : 0;

    for (int t0 = 0; t0 < T_TOK; t0 += 1024) {
        const int t = t0 + tid;
        const int f = ((int)idxA[t] == e);
        const unsigned long long m = __ballot(f);
        const int pre = __popcll(m & below);
        const int tot = __popcll(m);
        if (lane == 0) wtot[w] = tot;
        __syncthreads();
        int off = 0, all = 0;
#pragma unroll
        for (int i = 0; i < 16; i++) {
            const int v = wtot[i];
            if (i < w) off += v;
            all += v;
        }
        if (f) {
            const int rank = base + off + pre;
            loc[t] = (rank < CAP) ? (float)rank : 0.0f;
        }
        base += all;
        __syncthreads();
    }
}

// ---------------------------------------------------------------------------
// Kernel C: l_aux = sum(me * min(cnt1,CAP)) * E/(T*T); plus constants.
// ---------------------------------------------------------------------------
__global__ __launch_bounds__(128) void finalize_kernel(
    const float* __restrict__ me, const int* __restrict__ cnt1,
    float* __restrict__ out)
{
    __shared__ float red[2];
    const int tid = threadIdx.x;
    const int c = cnt1[tid];
    float p = me[tid] * (float)((c < CAP) ? c : CAP);
#pragma unroll
    for (int o = 32; o > 0; o >>= 1) p += __shfl_down(p, o);
    if ((tid & 63) == 0) red[tid >> 6] = p;
    __syncthreads();
    if (tid == 0) {
        const float tot = red[0] + red[1];
        out[0] = tot * ((float)E_EXP / ((float)T_TOK * (float)T_TOK));
        out[1] = (float)CAP;
        out[2] = (float)E_EXP;
    }
}

extern "C" void kernel_launch(void* const* d_in, const int* in_sizes, int n_in,
                              void* d_out, int out_size, void* d_ws, size_t ws_size,
                              hipStream_t stream)
{
    const float* x  = (const float*)d_in[0];
    const float* wg = (const float*)d_in[1];
    float* out = (float*)d_out;

    float* me   = (float*)d_ws;                      // 128 floats
    int*   cnt1 = (int*)((char*)d_ws + 512);         // 128 ints
    _Float16* wt = (_Float16*)((char*)d_ws + 1024);  // 2 MB K-tiled planes

    hipMemsetAsync(d_ws, 0, 1024, stream);
    prep_wt<<<256, 256, 0, stream>>>(wg, wt);
    gemm_gate<<<T_TOK / BM, 1024, 0, stream>>>(x, wt, out, me, cnt1);
    rank_kernel<<<2 * E_EXP, 1024, 0, stream>>>(out, cnt1);
    finalize_kernel<<<1, 128, 0, stream>>>(me, cnt1, out);
}